// Round 10
// baseline (572.214 us; speedup 1.0000x reference)
//
#include <hip/hip_runtime.h>
#include <stdint.h>

typedef unsigned short u16;
typedef float f32x4 __attribute__((ext_vector_type(4)));
typedef _Float16 half8 __attribute__((ext_vector_type(8)));
typedef __fp16 fp16x2 __attribute__((ext_vector_type(2)));

#define B_  8
#define M_  2
#define DK_ 512
#define D_  256
#define N_  2048
#define DV_ 512

#define OUT_FLOATS (B_*N_*DV_)     /* 8388608 */
#define QB_U16     (B_*M_*N_*D_)   /* 8388608 u16 elements = 16 MiB */

// ---- fp16 pack/unpack helpers -------------------------------------------
__device__ __forceinline__ uint32_t pk16(float a, float b){
    fp16x2 h = __builtin_amdgcn_cvt_pkrtz(a, b);      // v_cvt_pkrtz_f16_f32
    return __builtin_bit_cast(uint32_t, h);
}
__device__ __forceinline__ float h2f_lo(uint32_t u){
    return (float)__builtin_bit_cast(_Float16, (unsigned short)(u & 0xffffu));
}
__device__ __forceinline__ float h2f_hi(uint32_t u){
    return (float)__builtin_bit_cast(_Float16, (unsigned short)(u >> 16));
}

// ============================================================
// K0: transpose-convert qt,kt (fp32 [b, m*256+c, i]) -> f16 [ (b*2+m), row, c ]
// staged into the d_out "output" region. Also folds bar-sum (k1).
// ============================================================
__global__ __launch_bounds__(256) void k0_transpose(const float* __restrict__ qt,
                                                    const float* __restrict__ kt,
                                                    u16* __restrict__ dstBase,
                                                    float* __restrict__ wsBar){
    const int it = blockIdx.x, yc = blockIdx.y, z = blockIdx.z;
    const int b = z & 7, src = z >> 3;
    const float* sp = src ? kt : qt;
    u16* dp = dstBase + (size_t)src * QB_U16;
    const int m = yc >> 2;
    const int cbase = (yc & 3) * 64;
    const int i0 = it * 64;
    __shared__ u16 lds[64 * 72];   // [i][c], pad 72 keeps 16B alignment
    const int t = threadIdx.x;
    {
        const int c_loc = t >> 2;
        const int iq = (t & 3) * 16;
        const float* g = sp + (size_t)(b*DK_ + m*D_ + cbase + c_loc) * N_ + i0 + iq;
        float vv[16];
        *(float4*)&vv[0]  = *(const float4*)(g + 0);
        *(float4*)&vv[4]  = *(const float4*)(g + 4);
        *(float4*)&vv[8]  = *(const float4*)(g + 8);
        *(float4*)&vv[12] = *(const float4*)(g + 12);
        #pragma unroll
        for (int e = 0; e < 16; ++e){
            _Float16 hf = (_Float16)vv[e];
            lds[(iq + e)*72 + c_loc] = __builtin_bit_cast(unsigned short, hf);
        }
        if (src == 0){   // folded k1: partial sum over this thread's 16 i
            float s = 0.f;
            #pragma unroll
            for (int e = 0; e < 16; ++e) s += vv[e];
            s += __shfl_xor(s, 1);
            s += __shfl_xor(s, 2);
            if ((t & 3) == 0)
                atomicAdd(&wsBar[b*DK_ + m*D_ + cbase + c_loc], s);
        }
    }
    __syncthreads();
    {
        const int i_loc = t >> 2;
        const int cq = (t & 3) * 16;
        uint4 a  = *(const uint4*)&lds[i_loc*72 + cq];
        uint4 b2 = *(const uint4*)&lds[i_loc*72 + cq + 8];
        u16* o = dp + (size_t)((b*M_ + m)*N_ + i0 + i_loc) * D_ + cbase + cq;
        *(uint4*)o = a;
        *(uint4*)(o + 8) = b2;
    }
}

// ============================================================
// K0v: vt fp32 [b][dv][j] -> vF f16 fragment-tiled:
// vF[b][jc(64)][g(4)][dv(512)][8 f16]  (one 32KB contiguous slab per chunk)
// ============================================================
__global__ __launch_bounds__(256) void k0_vconv(const float* __restrict__ vt,
                                                u16* __restrict__ vF){
    const int idx = blockIdx.x * 256 + threadIdx.x;   // 0 .. 2^20-1
    const int dv = idx & 511;
    const int g  = (idx >> 9) & 3;
    const int jc = (idx >> 11) & 63;
    const int b  = idx >> 17;
    const float* src = vt + ((size_t)(b*DV_ + dv))*N_ + jc*32 + g*8;
    float4 f0 = *(const float4*)src;
    float4 f1 = *(const float4*)(src + 4);
    uint4 o;
    o.x = pk16(f0.x, f0.y);
    o.y = pk16(f0.z, f0.w);
    o.z = pk16(f1.x, f1.y);
    o.w = pk16(f1.z, f1.w);
    *(uint4*)(vF + (size_t)idx * 8) = o;
}

// ============================================================
// K2: logits[b*2+m] = (sum_c weight[m,c] * barSum[b,c]) / N
// ============================================================
__global__ void k2_logits(const float* __restrict__ wgt,
                          const float* __restrict__ bar,
                          float* __restrict__ wsLog){
    const int bm = blockIdx.x;
    const int b = bm >> 1, m = bm & 1;
    const int l = threadIdx.x; // 64
    float s = 0.f;
    #pragma unroll
    for (int k = 0; k < 8; ++k){
        const int c = l + k*64;
        s += wgt[m*DK_ + c] * bar[b*DK_ + c];
    }
    s += __shfl_xor(s, 1); s += __shfl_xor(s, 2); s += __shfl_xor(s, 4);
    s += __shfl_xor(s, 8); s += __shfl_xor(s, 16); s += __shfl_xor(s, 32);
    if (l == 0) wsLog[bm] = s * (1.f / (float)N_);
}

// ============================================================
// K3: S = q·k for both mixtures, E = exp(S/sqrt(512)) packed as f16 pair
// (m0 lo, m1 hi) into the dword that will later hold attn[b,i,j] fp32.
// Epilogue accumulates per-row exp-sums into wsSum via atomics.
// ============================================================
__global__ __launch_bounds__(256, 2) void k3_qk(const u16* __restrict__ qB,
                                                const u16* __restrict__ kB,
                                                uint32_t* __restrict__ attnE,
                                                float* __restrict__ wsSum){
    const int jt = blockIdx.x, it = blockIdx.y, b = blockIdx.z;
    const int t = threadIdx.x;
    const int w = t >> 6, l = t & 63;
    const int wi = w & 1, wj = w >> 1;
    const int l15 = l & 15, lq = l >> 4;
    __shared__ u16 lds[4 * 128 * 64];   // [tile=qk*2+m][row][c(64, swizzled granules)]

    f32x4 acc[2][4][4] = {};

    const int srow = t >> 1, shalf = t & 1;
    for (int bk = 0; bk < 4; ++bk){
        #pragma unroll
        for (int tile = 0; tile < 4; ++tile){     // 0,1 = q(m0,m1); 2,3 = k(m0,m1)
            const int qk = tile >> 1, m = tile & 1;
            const u16* sp = qk ? kB : qB;
            const int row0 = (qk ? jt : it) * 128;
            const u16* g = sp + (size_t)((b*M_ + m)*N_ + row0 + srow) * D_ + bk*64 + shalf*32;
            const uint4* gp = (const uint4*)g;
            uint4 v0 = gp[0], v1 = gp[1], v2 = gp[2], v3 = gp[3];
            u16* base = &lds[(tile*128 + srow) * 64];
            const int rs = srow & 7;
            *(uint4*)&base[((shalf*4 + 0) ^ rs) * 8] = v0;
            *(uint4*)&base[((shalf*4 + 1) ^ rs) * 8] = v1;
            *(uint4*)&base[((shalf*4 + 2) ^ rs) * 8] = v2;
            *(uint4*)&base[((shalf*4 + 3) ^ rs) * 8] = v3;
        }
        __syncthreads();
        #pragma unroll
        for (int ks = 0; ks < 2; ++ks){
            #pragma unroll
            for (int m = 0; m < 2; ++m){
                half8 a[4], bb[4];
                #pragma unroll
                for (int ti = 0; ti < 4; ++ti){
                    const int row = wi*64 + ti*16 + l15;
                    const int gr = (ks*4 + lq) ^ (row & 7);
                    a[ti] = *(const half8*)&lds[(m*128 + row)*64 + gr*8];
                }
                #pragma unroll
                for (int tj = 0; tj < 4; ++tj){
                    const int row = wj*64 + tj*16 + l15;
                    const int gr = (ks*4 + lq) ^ (row & 7);
                    bb[tj] = *(const half8*)&lds[((2 + m)*128 + row)*64 + gr*8];
                }
                #pragma unroll
                for (int ti = 0; ti < 4; ++ti)
                    #pragma unroll
                    for (int tj = 0; tj < 4; ++tj)
                        acc[m][ti][tj] = __builtin_amdgcn_mfma_f32_16x16x32_f16(
                            a[ti], bb[tj], acc[m][ti][tj], 0, 0, 0);
            }
        }
        __syncthreads();
    }

    const float INVT = 0.04419417382415922f;   // 1/sqrt(512)
    uint32_t* op = attnE + (size_t)b * N_ * N_;
    const int ibase = it*128 + wi*64;
    const int jbase = jt*128 + wj*64;
    #pragma unroll
    for (int ti = 0; ti < 4; ++ti){
        float rs[2][4] = {};   // [mixture][rr] partial row sums over this wave's j
        #pragma unroll
        for (int tj = 0; tj < 4; ++tj){
            #pragma unroll
            for (int rr = 0; rr < 4; ++rr){
                const int i = ibase + ti*16 + lq*4 + rr;   // C/D: row=(l>>4)*4+reg
                const int j = jbase + tj*16 + l15;         //      col=l&15
                const float e0 = __expf(acc[0][ti][tj][rr] * INVT);
                const float e1 = __expf(acc[1][ti][tj][rr] * INVT);
                op[(size_t)i * N_ + j] = pk16(e0, e1);
                rs[0][rr] += e0;
                rs[1][rr] += e1;
            }
        }
        #pragma unroll
        for (int m2 = 0; m2 < 2; ++m2){
            #pragma unroll
            for (int rr = 0; rr < 4; ++rr){
                float s = rs[m2][rr];
                s += __shfl_xor(s, 1); s += __shfl_xor(s, 2);
                s += __shfl_xor(s, 4); s += __shfl_xor(s, 8);
                if (l15 == 0)
                    atomicAdd(&wsSum[(size_t)(b*M_ + m2)*N_ + ibase + ti*16 + lq*4 + rr], s);
            }
        }
    }
}

// ============================================================
// K4 v7: r3 skeleton + surgical fixes.
// 256 threads = 4 waves (= 4 dv-quarters, each doing BOTH rowgroups ->
// zero v-read duplication in LDS); 32 rows/block; grid 512 (2 blocks/CU,
// 64KB LDS). v staged from fragment-tiled vF slab into [g][dv][8] LDS
// layout (measured zero bank conflicts, r8). E read scattered from
// global/L2 (r3-proven). attn fp32 stored in place post-prior-barrier
// (safe: __syncthreads drains vmcnt, so E(c) loads from iter c-1 are
// complete before iter c's store). 1-D grid with b = id&7 pins each
// batch to one XCD so v[b] (2MB) stays L2-resident.
// ============================================================
template<bool HASVB>
__global__ __launch_bounds__(256, 2) void k4_pv(const float* __restrict__ vt,
                                                const u16* __restrict__ vF,
                                                const float* __restrict__ wsLog,
                                                const float* __restrict__ wsSum,
                                                uint32_t* __restrict__ attnE,
                                                float* __restrict__ outO){
    const int id = blockIdx.x;
    const int b = id & 7, tile = id >> 3;      // XCD-pin: batch b -> XCD b
    const int i0 = tile * 32;
    const int t = threadIdx.x, l = t & 63, dvq = t >> 6;
    const int l15 = l & 15, lq = l >> 4;
    __shared__ u16 vbuf[2][16384];             // 64 KB: [g(4)][dv(512)][8 f16]

    const float lg0 = wsLog[b*2 + 0], lg1 = wsLog[b*2 + 1];
    const float pi0 = 1.f / (1.f + __expf(lg1 - lg0));
    const float pi1 = 1.f / (1.f + __expf(lg0 - lg1));

    float p0[2], p1[2];
    uint32_t* erow[2];
    #pragma unroll
    for (int rh = 0; rh < 2; ++rh){
        const int row = i0 + rh*16 + l15;
        p0[rh] = pi0 / wsSum[(size_t)(b*M_ + 0)*N_ + row];
        p1[rh] = pi1 / wsSum[(size_t)(b*M_ + 1)*N_ + row];
        erow[rh] = attnE + (size_t)(b*N_ + row) * N_;
    }

    const u16* vFb = vF + (size_t)b * (64 * 16384);

    uint4 svA[8], svB[8], eA[4], eB[4];

    auto loadV = [&](uint4 (&sv)[8], int c){
        const u16* p = vFb + (size_t)c * 16384;
        #pragma unroll
        for (int q = 0; q < 8; ++q)
            sv[q] = *(const uint4*)(p + q*2048 + t*8);
    };
    auto writeV = [&](int buf, uint4 (&sv)[8], int c){
        if (HASVB){
            #pragma unroll
            for (int q = 0; q < 8; ++q)
                *(uint4*)&vbuf[buf][q*2048 + t*8] = sv[q];   // quad = t&7: conflict-free
        } else {
            const int d0 = t * 2;
            #pragma unroll
            for (int r = 0; r < 2; ++r){
                const int dv = d0 + r;
                const float* src = vt + (size_t)(b*DV_ + dv)*N_ + c*32;
                #pragma unroll
                for (int g = 0; g < 4; ++g){
                    float4 f0 = *(const float4*)(src + g*8);
                    float4 f1 = *(const float4*)(src + g*8 + 4);
                    uint4 u;
                    u.x = pk16(f0.x, f0.y); u.y = pk16(f0.z, f0.w);
                    u.z = pk16(f1.x, f1.y); u.w = pk16(f1.z, f1.w);
                    *(uint4*)&vbuf[buf][g*4096 + dv*8] = u;
                }
            }
        }
    };
    auto loadE = [&](uint4 (&e)[4], int c){
        #pragma unroll
        for (int rh = 0; rh < 2; ++rh){
            const uint4* p = (const uint4*)(erow[rh] + c*32 + lq*8);
            e[rh*2 + 0] = p[0];
            e[rh*2 + 1] = p[1];
        }
    };

    f32x4 acc[2][8] = {};

    // prologue: chunk 0 into LDS, chunk 1 into regs
    if (HASVB) loadV(svA, 0);
    writeV(0, svA, 0);
    if (HASVB) loadV(svB, 1);
    loadE(eA, 0);
    __syncthreads();

    auto body = [&](int c, uint4 (&svW)[8], uint4 (&svL)[8],
                    uint4 (&ec)[4], uint4 (&en)[4]){
        if (HASVB && c + 2 < 64) loadV(svL, c + 2);   // hidden under body work
        if (c + 1 < 64) loadE(en, c + 1);

        float av[2][8];
        half8 af[2];
        #pragma unroll
        for (int rh = 0; rh < 2; ++rh){
            const uint4 u0 = ec[rh*2], u1 = ec[rh*2 + 1];
            av[rh][0] = p0[rh]*h2f_lo(u0.x) + p1[rh]*h2f_hi(u0.x);
            av[rh][1] = p0[rh]*h2f_lo(u0.y) + p1[rh]*h2f_hi(u0.y);
            av[rh][2] = p0[rh]*h2f_lo(u0.z) + p1[rh]*h2f_hi(u0.z);
            av[rh][3] = p0[rh]*h2f_lo(u0.w) + p1[rh]*h2f_hi(u0.w);
            av[rh][4] = p0[rh]*h2f_lo(u1.x) + p1[rh]*h2f_hi(u1.x);
            av[rh][5] = p0[rh]*h2f_lo(u1.y) + p1[rh]*h2f_hi(u1.y);
            av[rh][6] = p0[rh]*h2f_lo(u1.z) + p1[rh]*h2f_hi(u1.z);
            av[rh][7] = p0[rh]*h2f_lo(u1.w) + p1[rh]*h2f_hi(u1.w);
            uint4 ua;
            ua.x = pk16(av[rh][0], av[rh][1]);
            ua.y = pk16(av[rh][2], av[rh][3]);
            ua.z = pk16(av[rh][4], av[rh][5]);
            ua.w = pk16(av[rh][6], av[rh][7]);
            union { uint4 u; half8 h; } cv; cv.u = ua;
            af[rh] = cv.h;
        }
        // in-place attn fp32 store: E(c) loads (issued iter c-1) were drained
        // by the previous __syncthreads -> no reader left on these addresses.
        if (dvq < 2){
            float* ap = (float*)(erow[dvq] + c*32 + lq*8);
            *(float4*)ap       = make_float4(av[dvq][0], av[dvq][1], av[dvq][2], av[dvq][3]);
            *(float4*)(ap + 4) = make_float4(av[dvq][4], av[dvq][5], av[dvq][6], av[dvq][7]);
        }
        // PV MFMAs on vbuf[c&1] (written last iter, barrier-protected)
        const u16* vb = &vbuf[c & 1][lq*4096 + (dvq*128 + l15)*8];
        #pragma unroll
        for (int n = 0; n < 8; ++n){
            half8 bv = *(const half8*)(vb + n*128);
            acc[0][n] = __builtin_amdgcn_mfma_f32_16x16x32_f16(af[0], bv, acc[0][n], 0, 0, 0);
            acc[1][n] = __builtin_amdgcn_mfma_f32_16x16x32_f16(af[1], bv, acc[1][n], 0, 0, 0);
        }
        if (c + 1 < 64) writeV((c + 1) & 1, svW, c + 1);
        __syncthreads();
    };

    for (int c = 0; c < 64; c += 2){
        body(c,     svB, svA, eA, eB);
        body(c + 1, svA, svB, eB, eA);
    }

    #pragma unroll
    for (int n = 0; n < 8; ++n){
        #pragma unroll
        for (int rh = 0; rh < 2; ++rh){
            #pragma unroll
            for (int rr = 0; rr < 4; ++rr){
                const int i  = i0 + rh*16 + lq*4 + rr;   // C/D: row=(l>>4)*4+reg
                const int dv = dvq*128 + n*16 + l15;     //      col=l&15
                outO[(size_t)(b*N_ + i)*DV_ + dv] = acc[rh][n][rr];
            }
        }
    }
}

// ============================================================
extern "C" void kernel_launch(void* const* d_in, const int* in_sizes, int n_in,
                              void* d_out, int out_size, void* d_ws, size_t ws_size,
                              hipStream_t stream){
    const float* qt  = (const float*)d_in[0];
    const float* kt  = (const float*)d_in[1];
    const float* vt  = (const float*)d_in[2];
    const float* wgt = (const float*)d_in[3];

    float* wsLog = (float*)d_ws;                         // 16 floats
    float* wsBar = (float*)((char*)d_ws + 4096);         // 4096 floats
    float* wsSum = (float*)((char*)d_ws + 65536);        // 32768 floats (128 KiB)

    u16* stage = (u16*)d_out;                            // qB at 0, kB after it
    u16* kB = stage + QB_U16;
    uint32_t* attnE = (uint32_t*)d_out + OUT_FLOATS;     // attn region doubles as E scratch
    float* outO = (float*)d_out;

    const size_t vfBytes = (size_t)B_ * 64 * 16384 * 2;  // 16 MiB
    u16* vF = (ws_size >= (size_t)1048576 + vfBytes)
                  ? (u16*)((char*)d_ws + 1048576) : (u16*)nullptr;

    hipMemsetAsync(d_ws, 0, 262144, stream);             // zero wsLog/wsBar/wsSum

    k0_transpose<<<dim3(32, 8, 16), 256, 0, stream>>>(qt, kt, stage, wsBar);
    if (vF) k0_vconv<<<dim3(4096), 256, 0, stream>>>(vt, vF);
    k2_logits<<<dim3(16), 64, 0, stream>>>(wgt, wsBar, wsLog);
    k3_qk<<<dim3(16, 16, 8), 256, 0, stream>>>(stage, kB, attnE, wsSum);
    if (vF) k4_pv<true ><<<dim3(512), 256, 0, stream>>>(vt, vF, wsLog, wsSum, attnE, outO);
    else    k4_pv<false><<<dim3(512), 256, 0, stream>>>(vt, vF, wsLog, wsSum, attnE, outO);
}

// Round 11
// 359.276 us; speedup vs baseline: 1.5927x; 1.5927x over previous
//
#include <hip/hip_runtime.h>
#include <stdint.h>

typedef unsigned short u16;
typedef float f32x4 __attribute__((ext_vector_type(4)));
typedef _Float16 half8 __attribute__((ext_vector_type(8)));
typedef __fp16 fp16x2 __attribute__((ext_vector_type(2)));

#define B_  8
#define M_  2
#define DK_ 512
#define D_  256
#define N_  2048
#define DV_ 512

#define OUT_FLOATS (B_*N_*DV_)     /* 8388608 */
#define QB_U16     (B_*M_*N_*D_)   /* 8388608 u16 elements = 16 MiB */

// ---- fp16 pack/unpack helpers -------------------------------------------
__device__ __forceinline__ uint32_t pk16(float a, float b){
    fp16x2 h = __builtin_amdgcn_cvt_pkrtz(a, b);      // v_cvt_pkrtz_f16_f32
    return __builtin_bit_cast(uint32_t, h);
}
__device__ __forceinline__ float h2f_lo(uint32_t u){
    return (float)__builtin_bit_cast(_Float16, (unsigned short)(u & 0xffffu));
}
__device__ __forceinline__ float h2f_hi(uint32_t u){
    return (float)__builtin_bit_cast(_Float16, (unsigned short)(u >> 16));
}

// ============================================================
// K0: transpose-convert qt,kt (fp32 [b, m*256+c, i]) -> f16 [ (b*2+m), row, c ]
// staged into the d_out "output" region. Also folds bar-sum (k1).
// ============================================================
__global__ __launch_bounds__(256) void k0_transpose(const float* __restrict__ qt,
                                                    const float* __restrict__ kt,
                                                    u16* __restrict__ dstBase,
                                                    float* __restrict__ wsBar){
    const int it = blockIdx.x, yc = blockIdx.y, z = blockIdx.z;
    const int b = z & 7, src = z >> 3;
    const float* sp = src ? kt : qt;
    u16* dp = dstBase + (size_t)src * QB_U16;
    const int m = yc >> 2;
    const int cbase = (yc & 3) * 64;
    const int i0 = it * 64;
    __shared__ u16 lds[64 * 72];   // [i][c], pad 72 keeps 16B alignment
    const int t = threadIdx.x;
    {
        const int c_loc = t >> 2;
        const int iq = (t & 3) * 16;
        const float* g = sp + (size_t)(b*DK_ + m*D_ + cbase + c_loc) * N_ + i0 + iq;
        float vv[16];
        *(float4*)&vv[0]  = *(const float4*)(g + 0);
        *(float4*)&vv[4]  = *(const float4*)(g + 4);
        *(float4*)&vv[8]  = *(const float4*)(g + 8);
        *(float4*)&vv[12] = *(const float4*)(g + 12);
        #pragma unroll
        for (int e = 0; e < 16; ++e){
            _Float16 hf = (_Float16)vv[e];
            lds[(iq + e)*72 + c_loc] = __builtin_bit_cast(unsigned short, hf);
        }
        if (src == 0){   // folded k1: partial sum over this thread's 16 i
            float s = 0.f;
            #pragma unroll
            for (int e = 0; e < 16; ++e) s += vv[e];
            s += __shfl_xor(s, 1);
            s += __shfl_xor(s, 2);
            if ((t & 3) == 0)
                atomicAdd(&wsBar[b*DK_ + m*D_ + cbase + c_loc], s);
        }
    }
    __syncthreads();
    {
        const int i_loc = t >> 2;
        const int cq = (t & 3) * 16;
        uint4 a  = *(const uint4*)&lds[i_loc*72 + cq];
        uint4 b2 = *(const uint4*)&lds[i_loc*72 + cq + 8];
        u16* o = dp + (size_t)((b*M_ + m)*N_ + i0 + i_loc) * D_ + cbase + cq;
        *(uint4*)o = a;
        *(uint4*)(o + 8) = b2;
    }
}

// ============================================================
// K0v: vt fp32 [b][dv][j] -> vF f16 fragment-tiled:
// vF[b][jc(64)][g(4)][dv(512)][8 f16]  (one 32KB contiguous slab per chunk)
// ============================================================
__global__ __launch_bounds__(256) void k0_vconv(const float* __restrict__ vt,
                                                u16* __restrict__ vF){
    const int idx = blockIdx.x * 256 + threadIdx.x;   // 0 .. 2^20-1
    const int dv = idx & 511;
    const int g  = (idx >> 9) & 3;
    const int jc = (idx >> 11) & 63;
    const int b  = idx >> 17;
    const float* src = vt + ((size_t)(b*DV_ + dv))*N_ + jc*32 + g*8;
    float4 f0 = *(const float4*)src;
    float4 f1 = *(const float4*)(src + 4);
    uint4 o;
    o.x = pk16(f0.x, f0.y);
    o.y = pk16(f0.z, f0.w);
    o.z = pk16(f1.x, f1.y);
    o.w = pk16(f1.z, f1.w);
    *(uint4*)(vF + (size_t)idx * 8) = o;
}

// ============================================================
// K2: logits[b*2+m] = (sum_c weight[m,c] * barSum[b,c]) / N
// ============================================================
__global__ void k2_logits(const float* __restrict__ wgt,
                          const float* __restrict__ bar,
                          float* __restrict__ wsLog){
    const int bm = blockIdx.x;
    const int b = bm >> 1, m = bm & 1;
    const int l = threadIdx.x; // 64
    float s = 0.f;
    #pragma unroll
    for (int k = 0; k < 8; ++k){
        const int c = l + k*64;
        s += wgt[m*DK_ + c] * bar[b*DK_ + c];
    }
    s += __shfl_xor(s, 1); s += __shfl_xor(s, 2); s += __shfl_xor(s, 4);
    s += __shfl_xor(s, 8); s += __shfl_xor(s, 16); s += __shfl_xor(s, 32);
    if (l == 0) wsLog[bm] = s * (1.f / (float)N_);
}

// ============================================================
// K3: S = q·k for both mixtures, E = exp(S/sqrt(512)) packed as f16 pair
// (m0 lo, m1 hi) into the dword that will later hold attn[b,i,j] fp32.
// Epilogue accumulates per-row exp-sums into wsSum via atomics.
// ============================================================
__global__ __launch_bounds__(256, 2) void k3_qk(const u16* __restrict__ qB,
                                                const u16* __restrict__ kB,
                                                uint32_t* __restrict__ attnE,
                                                float* __restrict__ wsSum){
    const int jt = blockIdx.x, it = blockIdx.y, b = blockIdx.z;
    const int t = threadIdx.x;
    const int w = t >> 6, l = t & 63;
    const int wi = w & 1, wj = w >> 1;
    const int l15 = l & 15, lq = l >> 4;
    __shared__ u16 lds[4 * 128 * 64];   // [tile=qk*2+m][row][c(64, swizzled granules)]

    f32x4 acc[2][4][4] = {};

    const int srow = t >> 1, shalf = t & 1;
    for (int bk = 0; bk < 4; ++bk){
        #pragma unroll
        for (int tile = 0; tile < 4; ++tile){     // 0,1 = q(m0,m1); 2,3 = k(m0,m1)
            const int qk = tile >> 1, m = tile & 1;
            const u16* sp = qk ? kB : qB;
            const int row0 = (qk ? jt : it) * 128;
            const u16* g = sp + (size_t)((b*M_ + m)*N_ + row0 + srow) * D_ + bk*64 + shalf*32;
            const uint4* gp = (const uint4*)g;
            uint4 v0 = gp[0], v1 = gp[1], v2 = gp[2], v3 = gp[3];
            u16* base = &lds[(tile*128 + srow) * 64];
            const int rs = srow & 7;
            *(uint4*)&base[((shalf*4 + 0) ^ rs) * 8] = v0;
            *(uint4*)&base[((shalf*4 + 1) ^ rs) * 8] = v1;
            *(uint4*)&base[((shalf*4 + 2) ^ rs) * 8] = v2;
            *(uint4*)&base[((shalf*4 + 3) ^ rs) * 8] = v3;
        }
        __syncthreads();
        #pragma unroll
        for (int ks = 0; ks < 2; ++ks){
            #pragma unroll
            for (int m = 0; m < 2; ++m){
                half8 a[4], bb[4];
                #pragma unroll
                for (int ti = 0; ti < 4; ++ti){
                    const int row = wi*64 + ti*16 + l15;
                    const int gr = (ks*4 + lq) ^ (row & 7);
                    a[ti] = *(const half8*)&lds[(m*128 + row)*64 + gr*8];
                }
                #pragma unroll
                for (int tj = 0; tj < 4; ++tj){
                    const int row = wj*64 + tj*16 + l15;
                    const int gr = (ks*4 + lq) ^ (row & 7);
                    bb[tj] = *(const half8*)&lds[((2 + m)*128 + row)*64 + gr*8];
                }
                #pragma unroll
                for (int ti = 0; ti < 4; ++ti)
                    #pragma unroll
                    for (int tj = 0; tj < 4; ++tj)
                        acc[m][ti][tj] = __builtin_amdgcn_mfma_f32_16x16x32_f16(
                            a[ti], bb[tj], acc[m][ti][tj], 0, 0, 0);
            }
        }
        __syncthreads();
    }

    const float INVT = 0.04419417382415922f;   // 1/sqrt(512)
    uint32_t* op = attnE + (size_t)b * N_ * N_;
    const int ibase = it*128 + wi*64;
    const int jbase = jt*128 + wj*64;
    #pragma unroll
    for (int ti = 0; ti < 4; ++ti){
        float rs[2][4] = {};   // [mixture][rr] partial row sums over this wave's j
        #pragma unroll
        for (int tj = 0; tj < 4; ++tj){
            #pragma unroll
            for (int rr = 0; rr < 4; ++rr){
                const int i = ibase + ti*16 + lq*4 + rr;   // C/D: row=(l>>4)*4+reg
                const int j = jbase + tj*16 + l15;         //      col=l&15
                const float e0 = __expf(acc[0][ti][tj][rr] * INVT);
                const float e1 = __expf(acc[1][ti][tj][rr] * INVT);
                op[(size_t)i * N_ + j] = pk16(e0, e1);
                rs[0][rr] += e0;
                rs[1][rr] += e1;
            }
        }
        #pragma unroll
        for (int m2 = 0; m2 < 2; ++m2){
            #pragma unroll
            for (int rr = 0; rr < 4; ++rr){
                float s = rs[m2][rr];
                s += __shfl_xor(s, 1); s += __shfl_xor(s, 2);
                s += __shfl_xor(s, 4); s += __shfl_xor(s, 8);
                if (l15 == 0)
                    atomicAdd(&wsSum[(size_t)(b*M_ + m2)*N_ + ibase + ti*16 + lq*4 + rr], s);
            }
        }
    }
}

// ============================================================
// K4 v8: r3 skeleton + proven-good substitutions ONLY.
// 512 threads = 8 waves = 2 rowgroups(32r) x 4 dv-quarters(128dv);
// 64-row tiles; grid (32,8) 2D (NO XCD pin — r10 showed pinning thrashes L2).
// v staged from contiguous vF slab into zero-conflict [g(4)][dv(512)][8]
// LDS layout (measured 0 conflicts, v6/v7); dv-quarter waves give 2x (not
// 4x) LDS read amplification. E scattered loads + in-place attn fp32 store
// (r3-proven, WRITE 165MB). Deep prefetch: v regs 2 chunks ahead, E 1 chunk
// ahead; ONE __syncthreads per chunk.
// ============================================================
template<bool HASVB>
__global__ __launch_bounds__(512) void k4_pv(const float* __restrict__ vt,
                                             const u16* __restrict__ vF,
                                             const float* __restrict__ wsLog,
                                             const float* __restrict__ wsSum,
                                             uint32_t* __restrict__ attnE,
                                             float* __restrict__ outO){
    const int tile = blockIdx.x, b = blockIdx.y;
    const int i0 = tile * 64;
    const int t = threadIdx.x, l = t & 63, w = t >> 6;
    const int l15 = l & 15, lq = l >> 4;
    const int rg = w >> 2, dvq = w & 3;
    __shared__ u16 vbuf[2][16384];             // 64 KB: [g(4)][dv(512)][8 f16]

    const float lg0 = wsLog[b*2 + 0], lg1 = wsLog[b*2 + 1];
    const float pi0 = 1.f / (1.f + __expf(lg1 - lg0));
    const float pi1 = 1.f / (1.f + __expf(lg0 - lg1));

    float p0[2], p1[2];
    uint32_t* erow[2];
    #pragma unroll
    for (int rh = 0; rh < 2; ++rh){
        const int row = i0 + rg*32 + rh*16 + l15;
        p0[rh] = pi0 / wsSum[(size_t)(b*M_ + 0)*N_ + row];
        p1[rh] = pi1 / wsSum[(size_t)(b*M_ + 1)*N_ + row];
        erow[rh] = attnE + (size_t)(b*N_ + row) * N_;
    }

    const u16* vFb = vF + (size_t)b * (64 * 16384);

    uint4  svA[4], svB[4];     // vF staging regs (32 KB / 512 threads = 4 uint4)
    float4 rfA[8], rfB[8];     // fallback staging regs
    uint4  eA[4],  eB[4];

    auto loadV = [&](uint4 (&sv)[4], int c){
        const u16* p = vFb + (size_t)c * 16384;
        #pragma unroll
        for (int q = 0; q < 4; ++q)
            sv[q] = *(const uint4*)(p + q*4096 + t*8);
    };
    auto loadVf = [&](float4 (&rf)[8], int c){
        const float* src = vt + (size_t)(b*DV_ + t)*N_ + c*32;
        #pragma unroll
        for (int q = 0; q < 8; ++q) rf[q] = *(const float4*)(src + q*4);
    };
    auto writeV = [&](int buf, uint4 (&sv)[4]){
        #pragma unroll
        for (int q = 0; q < 4; ++q)
            *(uint4*)&vbuf[buf][q*4096 + t*8] = sv[q];     // contiguous: 0-conflict
    };
    auto writeVf = [&](int buf, float4 (&rf)[8]){
        #pragma unroll
        for (int g = 0; g < 4; ++g){
            uint4 u;
            u.x = pk16(rf[2*g].x,   rf[2*g].y);
            u.y = pk16(rf[2*g].z,   rf[2*g].w);
            u.z = pk16(rf[2*g+1].x, rf[2*g+1].y);
            u.w = pk16(rf[2*g+1].z, rf[2*g+1].w);
            *(uint4*)&vbuf[buf][g*4096 + t*8] = u;
        }
    };
    auto loadE = [&](uint4 (&e)[4], int c){
        #pragma unroll
        for (int rh = 0; rh < 2; ++rh){
            const uint4* p = (const uint4*)(erow[rh] + c*32 + lq*8);
            e[rh*2 + 0] = p[0];
            e[rh*2 + 1] = p[1];
        }
    };

    f32x4 acc[2][8] = {};

    // prologue: chunk 0 into LDS, chunk 1 into regs
    if (HASVB){ loadV(svA, 0); writeV(0, svA); loadV(svB, 1); }
    else      { loadVf(rfA, 0); writeVf(0, rfA); loadVf(rfB, 1); }
    loadE(eA, 0);
    __syncthreads();

    auto body = [&](int c, uint4 (&svW)[4], uint4 (&svL)[4],
                    float4 (&rfW)[8], float4 (&rfL)[8],
                    uint4 (&ec)[4], uint4 (&en)[4]){
        if (c + 1 < 64) loadE(en, c + 1);                    // in flight
        if (c + 2 < 64){ if (HASVB) loadV(svL, c + 2); else loadVf(rfL, c + 2); }

        float av[2][8];
        half8 af[2];
        #pragma unroll
        for (int rh = 0; rh < 2; ++rh){
            const uint4 u0 = ec[rh*2], u1 = ec[rh*2 + 1];    // drains E(c)
            av[rh][0] = p0[rh]*h2f_lo(u0.x) + p1[rh]*h2f_hi(u0.x);
            av[rh][1] = p0[rh]*h2f_lo(u0.y) + p1[rh]*h2f_hi(u0.y);
            av[rh][2] = p0[rh]*h2f_lo(u0.z) + p1[rh]*h2f_hi(u0.z);
            av[rh][3] = p0[rh]*h2f_lo(u0.w) + p1[rh]*h2f_hi(u0.w);
            av[rh][4] = p0[rh]*h2f_lo(u1.x) + p1[rh]*h2f_hi(u1.x);
            av[rh][5] = p0[rh]*h2f_lo(u1.y) + p1[rh]*h2f_hi(u1.y);
            av[rh][6] = p0[rh]*h2f_lo(u1.z) + p1[rh]*h2f_hi(u1.z);
            av[rh][7] = p0[rh]*h2f_lo(u1.w) + p1[rh]*h2f_hi(u1.w);
            uint4 ua;
            ua.x = pk16(av[rh][0], av[rh][1]);
            ua.y = pk16(av[rh][2], av[rh][3]);
            ua.z = pk16(av[rh][4], av[rh][5]);
            ua.w = pk16(av[rh][6], av[rh][7]);
            union { uint4 u; half8 h; } cv; cv.u = ua;
            af[rh] = cv.h;
        }
        // in-place attn store (dvq==0 wave of each rg stores its own rows;
        // other dvq waves' E(c) loads were issued an iter earlier -> already
        // in/through L2 before this store issues). r3-proven discipline.
        if (dvq == 0){
            #pragma unroll
            for (int rh = 0; rh < 2; ++rh){
                float* ap = (float*)(erow[rh] + c*32 + lq*8);
                *(float4*)ap       = make_float4(av[rh][0], av[rh][1], av[rh][2], av[rh][3]);
                *(float4*)(ap + 4) = make_float4(av[rh][4], av[rh][5], av[rh][6], av[rh][7]);
            }
        }
        // PV MFMAs on vbuf[c&1] (written last iter, barrier-protected)
        const u16* vb = &vbuf[c & 1][lq*4096 + (dvq*128 + l15)*8];
        #pragma unroll
        for (int n = 0; n < 8; ++n){
            half8 bv = *(const half8*)(vb + n*128);
            acc[0][n] = __builtin_amdgcn_mfma_f32_16x16x32_f16(af[0], bv, acc[0][n], 0, 0, 0);
            acc[1][n] = __builtin_amdgcn_mfma_f32_16x16x32_f16(af[1], bv, acc[1][n], 0, 0, 0);
        }
        if (c + 1 < 64){ if (HASVB) writeV((c + 1) & 1, svW); else writeVf((c + 1) & 1, rfW); }
        __syncthreads();
    };

    for (int c = 0; c < 64; c += 2){
        body(c,     svB, svA, rfB, rfA, eA, eB);
        body(c + 1, svA, svB, rfA, rfB, eB, eA);
    }

    #pragma unroll
    for (int n = 0; n < 8; ++n){
        #pragma unroll
        for (int rh = 0; rh < 2; ++rh){
            #pragma unroll
            for (int rr = 0; rr < 4; ++rr){
                const int i  = i0 + rg*32 + rh*16 + lq*4 + rr;  // C/D: row=(l>>4)*4+reg
                const int dv = dvq*128 + n*16 + l15;            //      col=l&15
                outO[(size_t)(b*N_ + i)*DV_ + dv] = acc[rh][n][rr];
            }
        }
    }
}

// ============================================================
extern "C" void kernel_launch(void* const* d_in, const int* in_sizes, int n_in,
                              void* d_out, int out_size, void* d_ws, size_t ws_size,
                              hipStream_t stream){
    const float* qt  = (const float*)d_in[0];
    const float* kt  = (const float*)d_in[1];
    const float* vt  = (const float*)d_in[2];
    const float* wgt = (const float*)d_in[3];

    float* wsLog = (float*)d_ws;                         // 16 floats
    float* wsBar = (float*)((char*)d_ws + 4096);         // 4096 floats
    float* wsSum = (float*)((char*)d_ws + 65536);        // 32768 floats (128 KiB)

    u16* stage = (u16*)d_out;                            // qB at 0, kB after it
    u16* kB = stage + QB_U16;
    uint32_t* attnE = (uint32_t*)d_out + OUT_FLOATS;     // attn region doubles as E scratch
    float* outO = (float*)d_out;

    const size_t vfBytes = (size_t)B_ * 64 * 16384 * 2;  // 16 MiB
    u16* vF = (ws_size >= (size_t)1048576 + vfBytes)
                  ? (u16*)((char*)d_ws + 1048576) : (u16*)nullptr;

    hipMemsetAsync(d_ws, 0, 262144, stream);             // zero wsLog/wsBar/wsSum

    k0_transpose<<<dim3(32, 8, 16), 256, 0, stream>>>(qt, kt, stage, wsBar);
    if (vF) k0_vconv<<<dim3(4096), 256, 0, stream>>>(vt, vF);
    k2_logits<<<dim3(16), 64, 0, stream>>>(wgt, wsBar, wsLog);
    k3_qk<<<dim3(16, 16, 8), 256, 0, stream>>>(stage, kB, attnE, wsSum);
    if (vF) k4_pv<true ><<<dim3(32, 8), 512, 0, stream>>>(vt, vF, wsLog, wsSum, attnE, outO);
    else    k4_pv<false><<<dim3(32, 8), 512, 0, stream>>>(vt, vF, wsLog, wsSum, attnE, outO);
}

// Round 12
// 276.023 us; speedup vs baseline: 2.0731x; 1.3016x over previous
//
#include <hip/hip_runtime.h>
#include <stdint.h>

typedef unsigned short u16;
typedef float f32x4 __attribute__((ext_vector_type(4)));
typedef _Float16 half8 __attribute__((ext_vector_type(8)));
typedef __fp16 fp16x2 __attribute__((ext_vector_type(2)));

#define B_  8
#define M_  2
#define DK_ 512
#define D_  256
#define N_  2048
#define DV_ 512

#define OUT_FLOATS (B_*N_*DV_)     /* 8388608 */
#define QB_U16     (B_*M_*N_*D_)   /* 8388608 u16 elements = 16 MiB */

// ---- fp16 pack/unpack helpers -------------------------------------------
__device__ __forceinline__ uint32_t pk16(float a, float b){
    fp16x2 h = __builtin_amdgcn_cvt_pkrtz(a, b);      // v_cvt_pkrtz_f16_f32
    return __builtin_bit_cast(uint32_t, h);
}
__device__ __forceinline__ float h2f_lo(uint32_t u){
    return (float)__builtin_bit_cast(_Float16, (unsigned short)(u & 0xffffu));
}
__device__ __forceinline__ float h2f_hi(uint32_t u){
    return (float)__builtin_bit_cast(_Float16, (unsigned short)(u >> 16));
}

// ============================================================
// K0: transpose-convert qt,kt (fp32 [b, m*256+c, i]) -> f16 [ (b*2+m), row, c ]
// staged into the d_out "output" region (32 MiB, dead until K4 writes O).
// ============================================================
__global__ __launch_bounds__(256) void k0_transpose(const float* __restrict__ qt,
                                                    const float* __restrict__ kt,
                                                    u16* __restrict__ dstBase){
    const int it = blockIdx.x, yc = blockIdx.y, z = blockIdx.z;
    const int b = z & 7, src = z >> 3;
    const float* sp = src ? kt : qt;
    u16* dp = dstBase + (size_t)src * QB_U16;
    const int m = yc >> 2;
    const int cbase = (yc & 3) * 64;
    const int i0 = it * 64;
    __shared__ u16 lds[64 * 72];   // [i][c], pad 72 keeps 16B alignment
    const int t = threadIdx.x;
    {
        const int c_loc = t >> 2;
        const int iq = (t & 3) * 16;
        const float* g = sp + (size_t)(b*DK_ + m*D_ + cbase + c_loc) * N_ + i0 + iq;
        float vv[16];
        *(float4*)&vv[0]  = *(const float4*)(g + 0);
        *(float4*)&vv[4]  = *(const float4*)(g + 4);
        *(float4*)&vv[8]  = *(const float4*)(g + 8);
        *(float4*)&vv[12] = *(const float4*)(g + 12);
        #pragma unroll
        for (int e = 0; e < 16; ++e){
            _Float16 hf = (_Float16)vv[e];
            lds[(iq + e)*72 + c_loc] = __builtin_bit_cast(unsigned short, hf);
        }
    }
    __syncthreads();
    {
        const int i_loc = t >> 2;
        const int cq = (t & 3) * 16;
        uint4 a  = *(const uint4*)&lds[i_loc*72 + cq];
        uint4 b2 = *(const uint4*)&lds[i_loc*72 + cq + 8];
        u16* o = dp + (size_t)((b*M_ + m)*N_ + i0 + i_loc) * D_ + cbase + cq;
        *(uint4*)o = a;
        *(uint4*)(o + 8) = b2;
    }
}

// ============================================================
// K0v (optional, only if ws is big enough): vt fp32 -> f16, same layout.
// ============================================================
__global__ __launch_bounds__(256) void k0_vconv(const float* __restrict__ vt,
                                                u16* __restrict__ vB){
    size_t idx = ((size_t)blockIdx.x * 256 + threadIdx.x) * 8;
    const size_t total = (size_t)B_ * DV_ * N_;
    if (idx < total){
        float4 f0 = *(const float4*)(vt + idx);
        float4 f1 = *(const float4*)(vt + idx + 4);
        uint4 o;
        o.x = pk16(f0.x, f0.y);
        o.y = pk16(f0.z, f0.w);
        o.z = pk16(f1.x, f1.y);
        o.w = pk16(f1.z, f1.w);
        *(uint4*)(vB + idx) = o;
    }
}

// ============================================================
// K1: bar[b][c] = mean_i qt[b][c][i]
// ============================================================
__global__ __launch_bounds__(256) void k1_bar(const float* __restrict__ qt,
                                              float* __restrict__ bar){
    const int cg = blockIdx.x, b = blockIdx.y;
    const int t = threadIdx.x;
    const int c = cg*8 + (t >> 5);
    const int seg = t & 31;
    const float* g = qt + (size_t)(b*DK_ + c)*N_ + seg*64;
    float s = 0.f;
    #pragma unroll
    for (int k = 0; k < 16; ++k){
        float4 f = *(const float4*)(g + k*4);
        s += f.x + f.y + f.z + f.w;
    }
    s += __shfl_xor(s, 1); s += __shfl_xor(s, 2); s += __shfl_xor(s, 4);
    s += __shfl_xor(s, 8); s += __shfl_xor(s, 16);
    if (seg == 0) bar[b*DK_ + c] = s * (1.f / (float)N_);
}

// ============================================================
// K2: logits[b*2+m] = sum_c weight[m,c] * bar[b,c]
// ============================================================
__global__ void k2_logits(const float* __restrict__ wgt,
                          const float* __restrict__ bar,
                          float* __restrict__ wsLog){
    const int bm = blockIdx.x;
    const int b = bm >> 1, m = bm & 1;
    const int l = threadIdx.x; // 64
    float s = 0.f;
    #pragma unroll
    for (int k = 0; k < 8; ++k){
        const int c = l + k*64;
        s += wgt[m*DK_ + c] * bar[b*DK_ + c];
    }
    s += __shfl_xor(s, 1); s += __shfl_xor(s, 2); s += __shfl_xor(s, 4);
    s += __shfl_xor(s, 8); s += __shfl_xor(s, 16); s += __shfl_xor(s, 32);
    if (l == 0) wsLog[bm] = s;
}

// ============================================================
// K3: S = q·k for both mixtures, E = exp(S/sqrt(512)) packed as f16 pair
// (m0 lo, m1 hi) into the dword that will later hold attn[b,i,j] fp32.
// ============================================================
__global__ __launch_bounds__(256, 2) void k3_qk(const u16* __restrict__ qB,
                                                const u16* __restrict__ kB,
                                                uint32_t* __restrict__ attnE){
    const int jt = blockIdx.x, it = blockIdx.y, b = blockIdx.z;
    const int t = threadIdx.x;
    const int w = t >> 6, l = t & 63;
    const int wi = w & 1, wj = w >> 1;
    const int l15 = l & 15, lq = l >> 4;
    __shared__ u16 lds[4 * 128 * 64];   // [tile=qk*2+m][row][c(64, swizzled granules)]

    f32x4 acc[2][4][4] = {};

    const int srow = t >> 1, shalf = t & 1;
    for (int bk = 0; bk < 4; ++bk){
        #pragma unroll
        for (int tile = 0; tile < 4; ++tile){     // 0,1 = q(m0,m1); 2,3 = k(m0,m1)
            const int qk = tile >> 1, m = tile & 1;
            const u16* sp = qk ? kB : qB;
            const int row0 = (qk ? jt : it) * 128;
            const u16* g = sp + (size_t)((b*M_ + m)*N_ + row0 + srow) * D_ + bk*64 + shalf*32;
            const uint4* gp = (const uint4*)g;
            uint4 v0 = gp[0], v1 = gp[1], v2 = gp[2], v3 = gp[3];
            u16* base = &lds[(tile*128 + srow) * 64];
            const int rs = srow & 7;
            *(uint4*)&base[((shalf*4 + 0) ^ rs) * 8] = v0;
            *(uint4*)&base[((shalf*4 + 1) ^ rs) * 8] = v1;
            *(uint4*)&base[((shalf*4 + 2) ^ rs) * 8] = v2;
            *(uint4*)&base[((shalf*4 + 3) ^ rs) * 8] = v3;
        }
        __syncthreads();
        #pragma unroll
        for (int ks = 0; ks < 2; ++ks){
            #pragma unroll
            for (int m = 0; m < 2; ++m){
                half8 a[4], bb[4];
                #pragma unroll
                for (int ti = 0; ti < 4; ++ti){
                    const int row = wi*64 + ti*16 + l15;
                    const int gr = (ks*4 + lq) ^ (row & 7);
                    a[ti] = *(const half8*)&lds[(m*128 + row)*64 + gr*8];
                }
                #pragma unroll
                for (int tj = 0; tj < 4; ++tj){
                    const int row = wj*64 + tj*16 + l15;
                    const int gr = (ks*4 + lq) ^ (row & 7);
                    bb[tj] = *(const half8*)&lds[((2 + m)*128 + row)*64 + gr*8];
                }
                #pragma unroll
                for (int ti = 0; ti < 4; ++ti)
                    #pragma unroll
                    for (int tj = 0; tj < 4; ++tj)
                        acc[m][ti][tj] = __builtin_amdgcn_mfma_f32_16x16x32_f16(
                            a[ti], bb[tj], acc[m][ti][tj], 0, 0, 0);
            }
        }
        __syncthreads();
    }

    const float INVT = 0.04419417382415922f;   // 1/sqrt(512)
    uint32_t* op = attnE + (size_t)b * N_ * N_;
    const int ibase = it*128 + wi*64;
    const int jbase = jt*128 + wj*64;
    #pragma unroll
    for (int ti = 0; ti < 4; ++ti){
        #pragma unroll
        for (int tj = 0; tj < 4; ++tj){
            #pragma unroll
            for (int rr = 0; rr < 4; ++rr){
                const int i = ibase + ti*16 + lq*4 + rr;   // C/D: row=(l>>4)*4+reg
                const int j = jbase + tj*16 + l15;         //      col=l&15
                const float e0 = __expf(acc[0][ti][tj][rr] * INVT);
                const float e1 = __expf(acc[1][ti][tj][rr] * INVT);
                op[(size_t)i * N_ + j] = pk16(e0, e1);
            }
        }
    }
}

// ============================================================
// K3.5: coalesced per-row sums of packed E, -> wsScale[b][i] = {pi0/s0, pi1/s1}.
// One wave per row: 64 lanes x uint4 = 1KB contiguous per instruction.
// ============================================================
__global__ __launch_bounds__(256) void k35_rowsum(const uint32_t* __restrict__ attnE,
                                                  const float* __restrict__ wsLog,
                                                  float* __restrict__ wsScale){
    const int blk = blockIdx.x;              // 4096 blocks, 4 rows each
    const int b = blk >> 9;
    const int w = threadIdx.x >> 6, l = threadIdx.x & 63;
    const int i = (blk & 511)*4 + w;
    const uint4* e = (const uint4*)(attnE + ((size_t)b*N_ + i)*N_);
    float s0 = 0.f, s1 = 0.f;
    #pragma unroll
    for (int k = 0; k < 8; ++k){
        uint4 u = e[k*64 + l];
        s0 += h2f_lo(u.x) + h2f_lo(u.y) + h2f_lo(u.z) + h2f_lo(u.w);
        s1 += h2f_hi(u.x) + h2f_hi(u.y) + h2f_hi(u.z) + h2f_hi(u.w);
    }
    s0 += __shfl_xor(s0, 1);  s1 += __shfl_xor(s1, 1);
    s0 += __shfl_xor(s0, 2);  s1 += __shfl_xor(s1, 2);
    s0 += __shfl_xor(s0, 4);  s1 += __shfl_xor(s1, 4);
    s0 += __shfl_xor(s0, 8);  s1 += __shfl_xor(s1, 8);
    s0 += __shfl_xor(s0, 16); s1 += __shfl_xor(s1, 16);
    s0 += __shfl_xor(s0, 32); s1 += __shfl_xor(s1, 32);
    if (l == 0){
        const float lg0 = wsLog[b*2 + 0], lg1 = wsLog[b*2 + 1];
        const float pi0 = 1.f / (1.f + __expf(lg1 - lg0));
        const float pi1 = 1.f / (1.f + __expf(lg0 - lg1));
        wsScale[((size_t)b*N_ + i)*2 + 0] = pi0 / s0;
        wsScale[((size_t)b*N_ + i)*2 + 1] = pi1 / s1;
    }
}

// ============================================================
// K4 v9: EXACT r3 (v2, 119.5us) structure; ONLY change = v LDS layout to the
// measured-zero-conflict slab [g(4)][dv(512)][8 f16] (r8/r9/r11: 0 conflicts
// for both the per-thread-contiguous write and the 16-lane-group read).
// 512 threads = 8 waves (4 row-groups x 2 dv-halves), 64 rows/block.
// Double-buffered v chunk in LDS, v loads + E loads prefetched one chunk
// ahead, two __syncthreads per chunk, in-place attn fp32 overwrite.
// ============================================================
template<bool HASVB>
__global__ __launch_bounds__(512) void k4_pv(const float* __restrict__ vt,
                                             const u16* __restrict__ vB,
                                             const float* __restrict__ wsScale,
                                             uint32_t* __restrict__ attnE,
                                             float* __restrict__ outO){
    const int itile = blockIdx.x, b = blockIdx.y;
    const int i0 = itile * 64;
    const int t = threadIdx.x;
    const int l = t & 63, w = t >> 6;
    const int l15 = l & 15, lq = l >> 4;
    const int rowgrp = w & 3, dvh = w >> 2;
    __shared__ u16 v_lds[2][16384];   // [g(4)][dv(512)][8] slabs — 0-conflict

    const int rl = rowgrp*16 + l15;                    // A-frag row (0..63)
    const float2 p01 = *(const float2*)&wsScale[((size_t)(b*N_ + i0 + rl))*2];
    const float p0 = p01.x, p1 = p01.y;
    uint32_t* erow = attnE + (size_t)(b*N_ + i0 + rl) * N_;

    const u16*   gv16 = vB + (size_t)(b*DV_ + t)*N_;
    const float* gv32 = vt + (size_t)(b*DV_ + t)*N_;

    uint4  rv[4];
    float4 rf[8];

    auto issue_load = [&](int c){
        const int j0 = c*32;
        if (HASVB){
            const uint4* gp = (const uint4*)(gv16 + j0);
            rv[0] = gp[0]; rv[1] = gp[1]; rv[2] = gp[2]; rv[3] = gp[3];
        } else {
            const float4* gp = (const float4*)(gv32 + j0);
            #pragma unroll
            for (int q = 0; q < 8; ++q) rf[q] = gp[q];
        }
    };
    auto write_lds = [&](int buf){
        #pragma unroll
        for (int G = 0; G < 4; ++G){
            uint4 u;
            if (HASVB){
                u = rv[G];
            } else {
                u.x = pk16(rf[2*G].x,   rf[2*G].y);
                u.y = pk16(rf[2*G].z,   rf[2*G].w);
                u.z = pk16(rf[2*G+1].x, rf[2*G+1].y);
                u.w = pk16(rf[2*G+1].z, rf[2*G+1].w);
            }
            *(uint4*)&v_lds[buf][G*4096 + t*8] = u;   // slab write: contiguous
        }
    };

    f32x4 acc[16] = {};

    issue_load(0);
    write_lds(0);
    issue_load(1);
    uint4 e0 = *(const uint4*)(erow + lq*8);
    uint4 e1 = *(const uint4*)(erow + lq*8 + 4);
    __syncthreads();

    int cur = 0;
    for (int c = 0; c < 64; ++c){
        if (c + 1 < 64) write_lds(cur ^ 1);            // chunk c+1 (loaded last iter)
        if (c + 2 < 64) issue_load(c + 2);             // in flight across barrier
        uint4 en0, en1;
        if (c + 1 < 64){                               // E prefetch for next chunk
            en0 = *(const uint4*)(erow + (c+1)*32 + lq*8);
            en1 = *(const uint4*)(erow + (c+1)*32 + lq*8 + 4);
        }
        float av[8];
        av[0] = p0*h2f_lo(e0.x) + p1*h2f_hi(e0.x);
        av[1] = p0*h2f_lo(e0.y) + p1*h2f_hi(e0.y);
        av[2] = p0*h2f_lo(e0.z) + p1*h2f_hi(e0.z);
        av[3] = p0*h2f_lo(e0.w) + p1*h2f_hi(e0.w);
        av[4] = p0*h2f_lo(e1.x) + p1*h2f_hi(e1.x);
        av[5] = p0*h2f_lo(e1.y) + p1*h2f_hi(e1.y);
        av[6] = p0*h2f_lo(e1.z) + p1*h2f_hi(e1.z);
        av[7] = p0*h2f_lo(e1.w) + p1*h2f_hi(e1.w);
        uint4 ua;
        ua.x = pk16(av[0], av[1]);
        ua.y = pk16(av[2], av[3]);
        ua.z = pk16(av[4], av[5]);
        ua.w = pk16(av[6], av[7]);
        union { uint4 u; half8 h; } cvt;
        cvt.u = ua;
        half8 af = cvt.h;

        __syncthreads();   // all E reads + v_lds writes complete

        // ---- overwrite the consumed E pairs with final attn fp32
        uint32_t* ep = erow + c*32 + lq*8;
        float4 w0 = make_float4(av[0], av[1], av[2], av[3]);
        float4 w1 = make_float4(av[4], av[5], av[6], av[7]);
        *(float4*)ep = w0;
        *(float4*)(ep + 4) = w1;

        // ---- PV: O[i, dv] += attn · v over this 32-j chunk
        const u16* vb = &v_lds[cur][lq*4096 + (dvh*256 + l15)*8];
        #pragma unroll
        for (int n = 0; n < 16; ++n){
            half8 bv = *(const half8*)(vb + n*128);    // dv stride 16 rows x 8 u16
            acc[n] = __builtin_amdgcn_mfma_f32_16x16x32_f16(af, bv, acc[n], 0, 0, 0);
        }
        if (c + 1 < 64){ e0 = en0; e1 = en1; }
        __syncthreads();   // protect v_lds for next chunk
        cur ^= 1;
    }

    #pragma unroll
    for (int n = 0; n < 16; ++n){
        #pragma unroll
        for (int rr = 0; rr < 4; ++rr){
            const int i  = i0 + rowgrp*16 + lq*4 + rr;  // C/D: row=(l>>4)*4+reg
            const int dv = dvh*256 + n*16 + l15;        //      col=l&15
            outO[(size_t)(b*N_ + i)*DV_ + dv] = acc[n][rr];
        }
    }
}

// ============================================================
extern "C" void kernel_launch(void* const* d_in, const int* in_sizes, int n_in,
                              void* d_out, int out_size, void* d_ws, size_t ws_size,
                              hipStream_t stream){
    const float* qt  = (const float*)d_in[0];
    const float* kt  = (const float*)d_in[1];
    const float* vt  = (const float*)d_in[2];
    const float* wgt = (const float*)d_in[3];

    float* ws      = (float*)d_ws;
    float* wsLog   = ws;          // 16 floats
    float* wsBar   = ws + 16;     // 4096 floats
    float* wsScale = (float*)((char*)d_ws + 32768);   // 32768 floats = 128 KiB

    u16* stage = (u16*)d_out;                        // qB at 0, kB after it
    u16* kB = stage + QB_U16;
    uint32_t* attnE = (uint32_t*)d_out + OUT_FLOATS; // attn region doubles as E scratch
    float* outO = (float*)d_out;

    const size_t vbBytes = (size_t)B_ * DV_ * N_ * 2;
    u16* vB = (ws_size >= (size_t)262144 + vbBytes)
                  ? (u16*)((char*)d_ws + 262144) : (u16*)nullptr;

    k0_transpose<<<dim3(32, 8, 16), 256, 0, stream>>>(qt, kt, stage);
    if (vB) k0_vconv<<<dim3(4096), 256, 0, stream>>>(vt, vB);
    k1_bar<<<dim3(64, 8), 256, 0, stream>>>(qt, wsBar);
    k2_logits<<<dim3(16), 64, 0, stream>>>(wgt, wsBar, wsLog);
    k3_qk<<<dim3(16, 16, 8), 256, 0, stream>>>(stage, kB, attnE);
    k35_rowsum<<<dim3(4096), 256, 0, stream>>>(attnE, wsLog, wsScale);
    if (vB) k4_pv<true ><<<dim3(32, 8), 512, 0, stream>>>(vt, vB, wsScale, attnE, outO);
    else    k4_pv<false><<<dim3(32, 8), 512, 0, stream>>>(vt, vB, wsScale, attnE, outO);
}

// Round 13
// 239.308 us; speedup vs baseline: 2.3911x; 1.1534x over previous
//
#include <hip/hip_runtime.h>
#include <stdint.h>

typedef unsigned short u16;
typedef float f32x4 __attribute__((ext_vector_type(4)));
typedef _Float16 half8 __attribute__((ext_vector_type(8)));
typedef __fp16 fp16x2 __attribute__((ext_vector_type(2)));

#define B_  8
#define M_  2
#define DK_ 512
#define D_  256
#define N_  2048
#define DV_ 512

#define OUT_FLOATS (B_*N_*DV_)     /* 8388608 */
#define QB_U16     (B_*M_*N_*D_)   /* 8388608 u16 elements = 16 MiB */

// ---- fp16 pack/unpack helpers -------------------------------------------
__device__ __forceinline__ uint32_t pk16(float a, float b){
    fp16x2 h = __builtin_amdgcn_cvt_pkrtz(a, b);      // v_cvt_pkrtz_f16_f32
    return __builtin_bit_cast(uint32_t, h);
}
__device__ __forceinline__ float h2f_lo(uint32_t u){
    return (float)__builtin_bit_cast(_Float16, (unsigned short)(u & 0xffffu));
}
__device__ __forceinline__ float h2f_hi(uint32_t u){
    return (float)__builtin_bit_cast(_Float16, (unsigned short)(u >> 16));
}

// ============================================================
// K0: transpose-convert qt,kt (fp32 [b, m*256+c, i]) -> f16 [ (b*2+m), row, c ]
// staged into the d_out "output" region (32 MiB, dead until K4 writes O).
// ============================================================
__global__ __launch_bounds__(256) void k0_transpose(const float* __restrict__ qt,
                                                    const float* __restrict__ kt,
                                                    u16* __restrict__ dstBase){
    const int it = blockIdx.x, yc = blockIdx.y, z = blockIdx.z;
    const int b = z & 7, src = z >> 3;
    const float* sp = src ? kt : qt;
    u16* dp = dstBase + (size_t)src * QB_U16;
    const int m = yc >> 2;
    const int cbase = (yc & 3) * 64;
    const int i0 = it * 64;
    __shared__ u16 lds[64 * 72];   // [i][c], pad 72 keeps 16B alignment
    const int t = threadIdx.x;
    {
        const int c_loc = t >> 2;
        const int iq = (t & 3) * 16;
        const float* g = sp + (size_t)(b*DK_ + m*D_ + cbase + c_loc) * N_ + i0 + iq;
        float vv[16];
        *(float4*)&vv[0]  = *(const float4*)(g + 0);
        *(float4*)&vv[4]  = *(const float4*)(g + 4);
        *(float4*)&vv[8]  = *(const float4*)(g + 8);
        *(float4*)&vv[12] = *(const float4*)(g + 12);
        #pragma unroll
        for (int e = 0; e < 16; ++e){
            _Float16 hf = (_Float16)vv[e];
            lds[(iq + e)*72 + c_loc] = __builtin_bit_cast(unsigned short, hf);
        }
    }
    __syncthreads();
    {
        const int i_loc = t >> 2;
        const int cq = (t & 3) * 16;
        uint4 a  = *(const uint4*)&lds[i_loc*72 + cq];
        uint4 b2 = *(const uint4*)&lds[i_loc*72 + cq + 8];
        u16* o = dp + (size_t)((b*M_ + m)*N_ + i0 + i_loc) * D_ + cbase + cq;
        *(uint4*)o = a;
        *(uint4*)(o + 8) = b2;
    }
}

// ============================================================
// K0v (optional, only if ws is big enough): vt fp32 -> f16, same layout.
// ============================================================
__global__ __launch_bounds__(256) void k0_vconv(const float* __restrict__ vt,
                                                u16* __restrict__ vB){
    size_t idx = ((size_t)blockIdx.x * 256 + threadIdx.x) * 8;
    const size_t total = (size_t)B_ * DV_ * N_;
    if (idx < total){
        float4 f0 = *(const float4*)(vt + idx);
        float4 f1 = *(const float4*)(vt + idx + 4);
        uint4 o;
        o.x = pk16(f0.x, f0.y);
        o.y = pk16(f0.z, f0.w);
        o.z = pk16(f1.x, f1.y);
        o.w = pk16(f1.z, f1.w);
        *(uint4*)(vB + idx) = o;
    }
}

// ============================================================
// K1: bar[b][c] = mean_i qt[b][c][i]
// ============================================================
__global__ __launch_bounds__(256) void k1_bar(const float* __restrict__ qt,
                                              float* __restrict__ bar){
    const int cg = blockIdx.x, b = blockIdx.y;
    const int t = threadIdx.x;
    const int c = cg*8 + (t >> 5);
    const int seg = t & 31;
    const float* g = qt + (size_t)(b*DK_ + c)*N_ + seg*64;
    float s = 0.f;
    #pragma unroll
    for (int k = 0; k < 16; ++k){
        float4 f = *(const float4*)(g + k*4);
        s += f.x + f.y + f.z + f.w;
    }
    s += __shfl_xor(s, 1); s += __shfl_xor(s, 2); s += __shfl_xor(s, 4);
    s += __shfl_xor(s, 8); s += __shfl_xor(s, 16);
    if (seg == 0) bar[b*DK_ + c] = s * (1.f / (float)N_);
}

// ============================================================
// K2: logits[b*2+m] = sum_c weight[m,c] * bar[b,c]
// ============================================================
__global__ void k2_logits(const float* __restrict__ wgt,
                          const float* __restrict__ bar,
                          float* __restrict__ wsLog){
    const int bm = blockIdx.x;
    const int b = bm >> 1, m = bm & 1;
    const int l = threadIdx.x; // 64
    float s = 0.f;
    #pragma unroll
    for (int k = 0; k < 8; ++k){
        const int c = l + k*64;
        s += wgt[m*DK_ + c] * bar[b*DK_ + c];
    }
    s += __shfl_xor(s, 1); s += __shfl_xor(s, 2); s += __shfl_xor(s, 4);
    s += __shfl_xor(s, 8); s += __shfl_xor(s, 16); s += __shfl_xor(s, 32);
    if (l == 0) wsLog[bm] = s;
}

// ============================================================
// K3: S = q·k for both mixtures, E = exp(S/sqrt(512)) packed as f16 pair
// (m0 lo, m1 hi) into the dword that will later hold attn[b,i,j] fp32.
// ============================================================
__global__ __launch_bounds__(256, 2) void k3_qk(const u16* __restrict__ qB,
                                                const u16* __restrict__ kB,
                                                uint32_t* __restrict__ attnE){
    const int jt = blockIdx.x, it = blockIdx.y, b = blockIdx.z;
    const int t = threadIdx.x;
    const int w = t >> 6, l = t & 63;
    const int wi = w & 1, wj = w >> 1;
    const int l15 = l & 15, lq = l >> 4;
    __shared__ u16 lds[4 * 128 * 64];   // [tile=qk*2+m][row][c(64, swizzled granules)]

    f32x4 acc[2][4][4] = {};

    const int srow = t >> 1, shalf = t & 1;
    for (int bk = 0; bk < 4; ++bk){
        #pragma unroll
        for (int tile = 0; tile < 4; ++tile){     // 0,1 = q(m0,m1); 2,3 = k(m0,m1)
            const int qk = tile >> 1, m = tile & 1;
            const u16* sp = qk ? kB : qB;
            const int row0 = (qk ? jt : it) * 128;
            const u16* g = sp + (size_t)((b*M_ + m)*N_ + row0 + srow) * D_ + bk*64 + shalf*32;
            const uint4* gp = (const uint4*)g;
            uint4 v0 = gp[0], v1 = gp[1], v2 = gp[2], v3 = gp[3];
            u16* base = &lds[(tile*128 + srow) * 64];
            const int rs = srow & 7;
            *(uint4*)&base[((shalf*4 + 0) ^ rs) * 8] = v0;
            *(uint4*)&base[((shalf*4 + 1) ^ rs) * 8] = v1;
            *(uint4*)&base[((shalf*4 + 2) ^ rs) * 8] = v2;
            *(uint4*)&base[((shalf*4 + 3) ^ rs) * 8] = v3;
        }
        __syncthreads();
        #pragma unroll
        for (int ks = 0; ks < 2; ++ks){
            #pragma unroll
            for (int m = 0; m < 2; ++m){
                half8 a[4], bb[4];
                #pragma unroll
                for (int ti = 0; ti < 4; ++ti){
                    const int row = wi*64 + ti*16 + l15;
                    const int gr = (ks*4 + lq) ^ (row & 7);
                    a[ti] = *(const half8*)&lds[(m*128 + row)*64 + gr*8];
                }
                #pragma unroll
                for (int tj = 0; tj < 4; ++tj){
                    const int row = wj*64 + tj*16 + l15;
                    const int gr = (ks*4 + lq) ^ (row & 7);
                    bb[tj] = *(const half8*)&lds[((2 + m)*128 + row)*64 + gr*8];
                }
                #pragma unroll
                for (int ti = 0; ti < 4; ++ti)
                    #pragma unroll
                    for (int tj = 0; tj < 4; ++tj)
                        acc[m][ti][tj] = __builtin_amdgcn_mfma_f32_16x16x32_f16(
                            a[ti], bb[tj], acc[m][ti][tj], 0, 0, 0);
            }
        }
        __syncthreads();
    }

    const float INVT = 0.04419417382415922f;   // 1/sqrt(512)
    uint32_t* op = attnE + (size_t)b * N_ * N_;
    const int ibase = it*128 + wi*64;
    const int jbase = jt*128 + wj*64;
    #pragma unroll
    for (int ti = 0; ti < 4; ++ti){
        #pragma unroll
        for (int tj = 0; tj < 4; ++tj){
            #pragma unroll
            for (int rr = 0; rr < 4; ++rr){
                const int i = ibase + ti*16 + lq*4 + rr;   // C/D: row=(l>>4)*4+reg
                const int j = jbase + tj*16 + l15;         //      col=l&15
                const float e0 = __expf(acc[0][ti][tj][rr] * INVT);
                const float e1 = __expf(acc[1][ti][tj][rr] * INVT);
                op[(size_t)i * N_ + j] = pk16(e0, e1);
            }
        }
    }
}

// ============================================================
// K3.5: coalesced per-row sums of packed E, -> wsScale[b][i] = {pi0/s0, pi1/s1}.
// One wave per row: 64 lanes x uint4 = 1KB contiguous per instruction.
// ============================================================
__global__ __launch_bounds__(256) void k35_rowsum(const uint32_t* __restrict__ attnE,
                                                  const float* __restrict__ wsLog,
                                                  float* __restrict__ wsScale){
    const int blk = blockIdx.x;              // 4096 blocks, 4 rows each
    const int b = blk >> 9;
    const int w = threadIdx.x >> 6, l = threadIdx.x & 63;
    const int i = (blk & 511)*4 + w;
    const uint4* e = (const uint4*)(attnE + ((size_t)b*N_ + i)*N_);
    float s0 = 0.f, s1 = 0.f;
    #pragma unroll
    for (int k = 0; k < 8; ++k){
        uint4 u = e[k*64 + l];
        s0 += h2f_lo(u.x) + h2f_lo(u.y) + h2f_lo(u.z) + h2f_lo(u.w);
        s1 += h2f_hi(u.x) + h2f_hi(u.y) + h2f_hi(u.z) + h2f_hi(u.w);
    }
    s0 += __shfl_xor(s0, 1);  s1 += __shfl_xor(s1, 1);
    s0 += __shfl_xor(s0, 2);  s1 += __shfl_xor(s1, 2);
    s0 += __shfl_xor(s0, 4);  s1 += __shfl_xor(s1, 4);
    s0 += __shfl_xor(s0, 8);  s1 += __shfl_xor(s1, 8);
    s0 += __shfl_xor(s0, 16); s1 += __shfl_xor(s1, 16);
    s0 += __shfl_xor(s0, 32); s1 += __shfl_xor(s1, 32);
    if (l == 0){
        const float lg0 = wsLog[b*2 + 0], lg1 = wsLog[b*2 + 1];
        const float pi0 = 1.f / (1.f + __expf(lg1 - lg0));
        const float pi1 = 1.f / (1.f + __expf(lg0 - lg1));
        wsScale[((size_t)b*N_ + i)*2 + 0] = pi0 / s0;
        wsScale[((size_t)b*N_ + i)*2 + 1] = pi1 / s1;
    }
}

// ============================================================
// K4 v10: r3 (v2) structure + zero-conflict slab LDS + the r3 store guard
// (if dvh==0) that r12 accidentally dropped (caused 2x attn write traffic).
// 512 threads = 8 waves (4 row-groups x 2 dv-halves), 64 rows/block.
// Double-buffered v chunk in LDS, v loads + E loads prefetched one chunk
// ahead, two __syncthreads per chunk, in-place attn fp32 overwrite.
// ============================================================
template<bool HASVB>
__global__ __launch_bounds__(512) void k4_pv(const float* __restrict__ vt,
                                             const u16* __restrict__ vB,
                                             const float* __restrict__ wsScale,
                                             uint32_t* __restrict__ attnE,
                                             float* __restrict__ outO){
    const int itile = blockIdx.x, b = blockIdx.y;
    const int i0 = itile * 64;
    const int t = threadIdx.x;
    const int l = t & 63, w = t >> 6;
    const int l15 = l & 15, lq = l >> 4;
    const int rowgrp = w & 3, dvh = w >> 2;
    __shared__ u16 v_lds[2][16384];   // [g(4)][dv(512)][8] slabs — 0-conflict

    const int rl = rowgrp*16 + l15;                    // A-frag row (0..63)
    const float2 p01 = *(const float2*)&wsScale[((size_t)(b*N_ + i0 + rl))*2];
    const float p0 = p01.x, p1 = p01.y;
    uint32_t* erow = attnE + (size_t)(b*N_ + i0 + rl) * N_;

    const u16*   gv16 = vB + (size_t)(b*DV_ + t)*N_;
    const float* gv32 = vt + (size_t)(b*DV_ + t)*N_;

    uint4  rv[4];
    float4 rf[8];

    auto issue_load = [&](int c){
        const int j0 = c*32;
        if (HASVB){
            const uint4* gp = (const uint4*)(gv16 + j0);
            rv[0] = gp[0]; rv[1] = gp[1]; rv[2] = gp[2]; rv[3] = gp[3];
        } else {
            const float4* gp = (const float4*)(gv32 + j0);
            #pragma unroll
            for (int q = 0; q < 8; ++q) rf[q] = gp[q];
        }
    };
    auto write_lds = [&](int buf){
        #pragma unroll
        for (int G = 0; G < 4; ++G){
            uint4 u;
            if (HASVB){
                u = rv[G];
            } else {
                u.x = pk16(rf[2*G].x,   rf[2*G].y);
                u.y = pk16(rf[2*G].z,   rf[2*G].w);
                u.z = pk16(rf[2*G+1].x, rf[2*G+1].y);
                u.w = pk16(rf[2*G+1].z, rf[2*G+1].w);
            }
            *(uint4*)&v_lds[buf][G*4096 + t*8] = u;   // slab write: contiguous
        }
    };

    f32x4 acc[16] = {};

    issue_load(0);
    write_lds(0);
    issue_load(1);
    uint4 e0 = *(const uint4*)(erow + lq*8);
    uint4 e1 = *(const uint4*)(erow + lq*8 + 4);
    __syncthreads();

    int cur = 0;
    for (int c = 0; c < 64; ++c){
        if (c + 1 < 64) write_lds(cur ^ 1);            // chunk c+1 (loaded last iter)
        if (c + 2 < 64) issue_load(c + 2);             // in flight across barrier
        uint4 en0, en1;
        if (c + 1 < 64){                               // E prefetch for next chunk
            en0 = *(const uint4*)(erow + (c+1)*32 + lq*8);
            en1 = *(const uint4*)(erow + (c+1)*32 + lq*8 + 4);
        }
        float av[8];
        av[0] = p0*h2f_lo(e0.x) + p1*h2f_hi(e0.x);
        av[1] = p0*h2f_lo(e0.y) + p1*h2f_hi(e0.y);
        av[2] = p0*h2f_lo(e0.z) + p1*h2f_hi(e0.z);
        av[3] = p0*h2f_lo(e0.w) + p1*h2f_hi(e0.w);
        av[4] = p0*h2f_lo(e1.x) + p1*h2f_hi(e1.x);
        av[5] = p0*h2f_lo(e1.y) + p1*h2f_hi(e1.y);
        av[6] = p0*h2f_lo(e1.z) + p1*h2f_hi(e1.z);
        av[7] = p0*h2f_lo(e1.w) + p1*h2f_hi(e1.w);
        uint4 ua;
        ua.x = pk16(av[0], av[1]);
        ua.y = pk16(av[2], av[3]);
        ua.z = pk16(av[4], av[5]);
        ua.w = pk16(av[6], av[7]);
        union { uint4 u; half8 h; } cvt;
        cvt.u = ua;
        half8 af = cvt.h;

        __syncthreads();   // all E reads + v_lds writes complete

        // ---- overwrite the consumed E pairs with final attn fp32
        // (dvh==0 waves only: ONE store per row — r3's guard, restored)
        if (dvh == 0){
            uint32_t* ep = erow + c*32 + lq*8;
            float4 w0 = make_float4(av[0], av[1], av[2], av[3]);
            float4 w1 = make_float4(av[4], av[5], av[6], av[7]);
            *(float4*)ep = w0;
            *(float4*)(ep + 4) = w1;
        }

        // ---- PV: O[i, dv] += attn · v over this 32-j chunk
        const u16* vb = &v_lds[cur][lq*4096 + (dvh*256 + l15)*8];
        #pragma unroll
        for (int n = 0; n < 16; ++n){
            half8 bv = *(const half8*)(vb + n*128);    // dv stride 16 rows x 8 u16
            acc[n] = __builtin_amdgcn_mfma_f32_16x16x32_f16(af, bv, acc[n], 0, 0, 0);
        }
        if (c + 1 < 64){ e0 = en0; e1 = en1; }
        __syncthreads();   // protect v_lds for next chunk
        cur ^= 1;
    }

    #pragma unroll
    for (int n = 0; n < 16; ++n){
        #pragma unroll
        for (int rr = 0; rr < 4; ++rr){
            const int i  = i0 + rowgrp*16 + lq*4 + rr;  // C/D: row=(l>>4)*4+reg
            const int dv = dvh*256 + n*16 + l15;        //      col=l&15
            outO[(size_t)(b*N_ + i)*DV_ + dv] = acc[n][rr];
        }
    }
}

// ============================================================
extern "C" void kernel_launch(void* const* d_in, const int* in_sizes, int n_in,
                              void* d_out, int out_size, void* d_ws, size_t ws_size,
                              hipStream_t stream){
    const float* qt  = (const float*)d_in[0];
    const float* kt  = (const float*)d_in[1];
    const float* vt  = (const float*)d_in[2];
    const float* wgt = (const float*)d_in[3];

    float* ws      = (float*)d_ws;
    float* wsLog   = ws;          // 16 floats
    float* wsBar   = ws + 16;     // 4096 floats
    float* wsScale = (float*)((char*)d_ws + 32768);   // 32768 floats = 128 KiB

    u16* stage = (u16*)d_out;                        // qB at 0, kB after it
    u16* kB = stage + QB_U16;
    uint32_t* attnE = (uint32_t*)d_out + OUT_FLOATS; // attn region doubles as E scratch
    float* outO = (float*)d_out;

    const size_t vbBytes = (size_t)B_ * DV_ * N_ * 2;
    u16* vB = (ws_size >= (size_t)262144 + vbBytes)
                  ? (u16*)((char*)d_ws + 262144) : (u16*)nullptr;

    k0_transpose<<<dim3(32, 8, 16), 256, 0, stream>>>(qt, kt, stage);
    if (vB) k0_vconv<<<dim3(4096), 256, 0, stream>>>(vt, vB);
    k1_bar<<<dim3(64, 8), 256, 0, stream>>>(qt, wsBar);
    k2_logits<<<dim3(16), 64, 0, stream>>>(wgt, wsBar, wsLog);
    k3_qk<<<dim3(16, 16, 8), 256, 0, stream>>>(stage, kB, attnE);
    k35_rowsum<<<dim3(4096), 256, 0, stream>>>(attnE, wsLog, wsScale);
    if (vB) k4_pv<true ><<<dim3(32, 8), 512, 0, stream>>>(vt, vB, wsScale, attnE, outO);
    else    k4_pv<false><<<dim3(32, 8), 512, 0, stream>>>(vt, vB, wsScale, attnE, outO);
}